// Round 8
// baseline (846.266 us; speedup 1.0000x reference)
//
#include <hip/hip_runtime.h>
#include <hip/hip_bf16.h>

#define B_ 16
#define S_ 2048
#define E_ 1024
#define M_ (B_ * S_)  // 32768

typedef unsigned short u16;
typedef float f32x4 __attribute__((ext_vector_type(4)));
typedef short s16x8 __attribute__((ext_vector_type(8)));
typedef unsigned short u16x8 __attribute__((ext_vector_type(8)));

__device__ __forceinline__ u16 f2bf(float f) {
    __hip_bfloat16 h = __float2bfloat16(f);
    return *reinterpret_cast<u16*>(&h);
}

__device__ __forceinline__ float bf2f(u16 v) {
    unsigned u = ((unsigned)v) << 16;
    return __uint_as_float(u);
}

__device__ __forceinline__ void gload_lds16(const void* g, void* lds) {
    __builtin_amdgcn_global_load_lds(
        (const __attribute__((address_space(1))) void*)g,
        (__attribute__((address_space(3))) void*)lds, 16, 0, 0);
}

// ---------------- fp32 -> bf16 conversion ----------------
__global__ __launch_bounds__(256) void cvt_f32_bf16(const float* __restrict__ src,
                                                    u16* __restrict__ dst, int n8) {
    for (int i = blockIdx.x * 256 + threadIdx.x; i < n8; i += gridDim.x * 256) {
        const float4* sp = (const float4*)src + (size_t)i * 2;
        float4 a = sp[0], b = sp[1];
        u16x8 o;
        o[0] = f2bf(a.x); o[1] = f2bf(a.y); o[2] = f2bf(a.z); o[3] = f2bf(a.w);
        o[4] = f2bf(b.x); o[5] = f2bf(b.y); o[6] = f2bf(b.z); o[7] = f2bf(b.w);
        *((u16x8*)dst + i) = o;
    }
}

// ---------------- V transpose: vt[b][d][s] = V[b][s][d] ----------------
__global__ __launch_bounds__(256) void transpose_v(const u16* __restrict__ V,
                                                   u16* __restrict__ vt) {
    int bid = blockIdx.x;  // 16 * 32 * 16
    int b = bid >> 9;
    int rem = bid & 511;
    int jt = rem >> 4, dt = rem & 15;
    __shared__ u16 lds[64 * 65];
    int t = threadIdx.x;
#pragma unroll
    for (int p = 0; p < 2; ++p) {
        int e = p * 2048 + t * 8;
        int j = e >> 6, d0 = e & 63;
        u16x8 v = *(const u16x8*)&V[((size_t)b * S_ + jt * 64 + j) * E_ + dt * 64 + d0];
#pragma unroll
        for (int q = 0; q < 8; ++q) lds[j * 65 + d0 + q] = v[q];
    }
    __syncthreads();
#pragma unroll
    for (int p = 0; p < 2; ++p) {
        int e = p * 2048 + t * 8;
        int d = e >> 6, j0 = e & 63;
        u16x8 o;
#pragma unroll
        for (int q = 0; q < 8; ++q) o[q] = lds[(j0 + q) * 65 + d];
        *(u16x8*)&vt[((size_t)b * E_ + dt * 64 + d) * S_ + jt * 64 + j0] = o;
    }
}

__device__ __forceinline__ int xcd_swizzle(int bid, int nwg) {
    int cpx = nwg >> 3;  // all grids divisible by 8
    return (bid & 7) * cpx + (bid >> 3);
}

// ======= 256x128 GEMM core, BK=32, 48KB LDS, 2 blocks/CU (TLP overlap) =======
// C = A * B^T, A:[M][KLEN], B:[N][KLEN] bf16 row-major.
// 512 thr = 8 waves (4M x 2N), wave-tile 64x64, acc[4][4] f32x4 (64 VGPR).
// LDS: buf{0,1} x [A 16KB | B 8KB] = 48KB -> 2 blocks/CU at launch_bounds(512,4).
// Theory: R3/R5 showed lockstep 1-block/CU serializes ds_read and MFMA clusters
// (~5300 cyc/tile vs 2480 MFMA floor). Two free-running blocks per CU let one
// block's MFMA phase cover the other's read/stage phase (m114 overlap).
// Swizzle (BK=32, 64B rows, 4x16B chunks): chunk ^= (row>>1)&3. Bank map for a
// frag read (16 rows x 4 chunks): each 8-lane group spans all 32 banks -> 0-way.
// Applied: inverse-swizzled gload SOURCE (dest linear) + swizzled ds_read.
// Schedule/tile: reads(8 b128) ; stage(kt+1) ; 16 MFMA ; lgkmcnt(0) ;
// vmcnt(0) ; barrier. Stage->wait depth = 1 full tile (~2000+ cyc, covers HBM).
template <int KLEN>
__device__ __forceinline__ void gemm_core(const u16* __restrict__ Abase,
                                          const u16* __restrict__ Bbase,
                                          char* lds, f32x4 acc[4][4], int tid) {
    constexpr int KT = KLEN / 32;
    const int w = tid >> 6, lane = tid & 63;
    const int wr = w >> 1, wc = w & 1;
    const int lr = lane & 15;
    const int ch = lane >> 4;  // k-chunk 0..3 (8 bf16 each)

    auto stage = [&](int kt) {
        if (kt >= KT) return;
        char* base = lds + (kt & 1) * 24576;
        // A: 256 rows x 64B = 16KB = 2 wave-issues of 1KB x 8 waves
#pragma unroll
        for (int i = 0; i < 2; ++i) {
            int o = i * 8192 + tid * 16;  // linear byte offset in A tile
            int row = o >> 6;
            int sc = ((o >> 4) & 3) ^ ((row >> 1) & 3);  // inverse-swizzled src chunk
            gload_lds16((const char*)Abase + (size_t)row * (KLEN * 2) + kt * 64 + sc * 16,
                        base + i * 8192 + w * 1024);
        }
        // B: 128 rows x 64B = 8KB = 1 wave-issue x 8 waves
        {
            int o = tid * 16;
            int row = o >> 6;
            int sc = ((o >> 4) & 3) ^ ((row >> 1) & 3);
            gload_lds16((const char*)Bbase + (size_t)row * (KLEN * 2) + kt * 64 + sc * 16,
                        base + 16384 + w * 1024);
        }
    };

    stage(0);
    asm volatile("s_waitcnt vmcnt(0)" ::: "memory");
    __builtin_amdgcn_s_barrier();

    s16x8 a[4], b[4];
#pragma unroll 1
    for (int kt = 0; kt < KT; ++kt) {
        const char* sA = lds + (kt & 1) * 24576;
        const char* sB = sA + 16384;
#pragma unroll
        for (int mi = 0; mi < 4; ++mi) {
            const int r = wr * 64 + mi * 16 + lr;
            a[mi] = *(const s16x8*)(sA + r * 64 + ((ch ^ ((r >> 1) & 3)) << 4));
        }
#pragma unroll
        for (int ni = 0; ni < 4; ++ni) {
            const int c = wc * 64 + ni * 16 + lr;
            b[ni] = *(const s16x8*)(sB + c * 64 + ((ch ^ ((c >> 1) & 3)) << 4));
        }
        stage(kt + 1);
        __builtin_amdgcn_s_setprio(1);
#pragma unroll
        for (int mi = 0; mi < 4; ++mi)
#pragma unroll
            for (int ni = 0; ni < 4; ++ni)
                acc[mi][ni] = __builtin_amdgcn_mfma_f32_16x16x32_bf16(
                    a[mi], b[ni], acc[mi][ni], 0, 0, 0);
        __builtin_amdgcn_s_setprio(0);
        asm volatile("s_waitcnt lgkmcnt(0)" ::: "memory");
        asm volatile("s_waitcnt vmcnt(0)" ::: "memory");
        __builtin_amdgcn_s_barrier();
    }
}

// ---------------- QKV projection: [32768,3072] = xb @ Wb^T + bias -> bf16 ----------------
__global__ __launch_bounds__(512, 4) void gemm_qkv(const u16* __restrict__ xb,
                                                   const u16* __restrict__ Wb,
                                                   const float* __restrict__ bq,
                                                   const float* __restrict__ bk,
                                                   const float* __restrict__ bvp,
                                                   u16* __restrict__ qkv) {
    __shared__ f32x4 smem[3072];  // 48 KiB
    char* lds = (char*)smem;
    int wg = xcd_swizzle(blockIdx.x, 3072);
    int mt = wg / 24, nt = wg % 24;  // 128 m-tiles(256) x 24 n-tiles(128)
    f32x4 acc[4][4];
    f32x4 zero = {0.f, 0.f, 0.f, 0.f};
#pragma unroll
    for (int i = 0; i < 4; ++i)
#pragma unroll
        for (int j = 0; j < 4; ++j) acc[i][j] = zero;
    gemm_core<E_>(xb + (size_t)mt * 256 * E_, Wb + (size_t)nt * 128 * E_, lds, acc,
                  threadIdx.x);

    int tid = threadIdx.x, w = tid >> 6, lane = tid & 63, wr = w >> 1, wc = w & 1;
    int mat = nt >> 3;  // 8 n-tiles(128) per matrix
    const float* bias = (mat == 0) ? bq : ((mat == 1) ? bk : bvp);
    u16* outm = qkv + (size_t)mat * M_ * E_;
    int bn = (nt & 7) * 128;
#pragma unroll
    for (int ni = 0; ni < 4; ++ni) {
        int n = bn + wc * 64 + ni * 16 + (lane & 15);
        float bb = bias[n];
#pragma unroll
        for (int mi = 0; mi < 4; ++mi)
#pragma unroll
            for (int j = 0; j < 4; ++j) {
                int m = mt * 256 + wr * 64 + mi * 16 + ((lane >> 4) << 2) + j;
                outm[(size_t)m * E_ + n] = f2bf(acc[mi][ni][j] + bb);
            }
    }
}

// ---------------- scores+exp -> bf16 P, row-sum atomics ----------------
__global__ __launch_bounds__(512, 4) void gemm_sexp(const u16* __restrict__ qkv,
                                                    u16* __restrict__ Pbuf,
                                                    float* __restrict__ lsum, int b0) {
    __shared__ f32x4 smem[3072];
    char* lds = (char*)smem;
    int wg = xcd_swizzle(blockIdx.x, gridDim.x);
    int ci = wg >> 7, rem = wg & 127, mt = rem >> 4, ntt = rem & 15;  // 8 x 16
    int bb = b0 + ci;
    const u16* Q = qkv + ((size_t)bb * S_ + mt * 256) * E_;
    const u16* K = qkv + (size_t)M_ * E_ + ((size_t)bb * S_ + ntt * 128) * E_;
    f32x4 acc[4][4];
    f32x4 zero = {0.f, 0.f, 0.f, 0.f};
#pragma unroll
    for (int i = 0; i < 4; ++i)
#pragma unroll
        for (int j = 0; j < 4; ++j) acc[i][j] = zero;
    gemm_core<E_>(Q, K, lds, acc, threadIdx.x);

    int tid = threadIdx.x, w = tid >> 6, lane = tid & 63, wr = w >> 1, wc = w & 1;
#pragma unroll
    for (int mi = 0; mi < 4; ++mi)
#pragma unroll
        for (int j = 0; j < 4; ++j) {
            int m = mt * 256 + wr * 64 + mi * 16 + ((lane >> 4) << 2) + j;
            size_t base = ((size_t)ci * S_ + m) * S_;
            float psum = 0.f;
            u16 pb[4];
#pragma unroll
            for (int ni = 0; ni < 4; ++ni) {
                float p = __expf(acc[mi][ni][j] * 0.03125f);
                pb[ni] = f2bf(p);
                psum += bf2f(pb[ni]);
            }
#pragma unroll
            for (int ni = 0; ni < 4; ++ni) {
                int n = ntt * 128 + wc * 64 + ni * 16 + (lane & 15);
                Pbuf[base + n] = pb[ni];
            }
            psum += __shfl_xor(psum, 1, 64);
            psum += __shfl_xor(psum, 2, 64);
            psum += __shfl_xor(psum, 4, 64);
            psum += __shfl_xor(psum, 8, 64);
            if ((lane & 15) == 0) atomicAdd(&lsum[(size_t)bb * S_ + m], psum);
        }
}

// ---------------- PV: out = (P @ vt^T) / lsum (fp32) ----------------
__global__ __launch_bounds__(512, 4) void gemm_pv(const u16* __restrict__ Pbuf,
                                                  const u16* __restrict__ vt,
                                                  const float* __restrict__ lsum,
                                                  float* __restrict__ out, int b0) {
    __shared__ f32x4 smem[3072];
    char* lds = (char*)smem;
    int wg = xcd_swizzle(blockIdx.x, gridDim.x);
    int ci = wg >> 6, rem = wg & 63, mt = rem >> 3, ntt = rem & 7;  // 8 x 8
    int bb = b0 + ci;
    const u16* A = Pbuf + (size_t)ci * S_ * S_ + (size_t)mt * 256 * S_;
    const u16* Bb = vt + ((size_t)bb * E_ + ntt * 128) * S_;
    f32x4 acc[4][4];
    f32x4 zero = {0.f, 0.f, 0.f, 0.f};
#pragma unroll
    for (int i = 0; i < 4; ++i)
#pragma unroll
        for (int j = 0; j < 4; ++j) acc[i][j] = zero;
    gemm_core<S_>(A, Bb, lds, acc, threadIdx.x);

    int tid = threadIdx.x, w = tid >> 6, lane = tid & 63, wr = w >> 1, wc = w & 1;
#pragma unroll
    for (int mi = 0; mi < 4; ++mi)
#pragma unroll
        for (int j = 0; j < 4; ++j) {
            int m = mt * 256 + wr * 64 + mi * 16 + ((lane >> 4) << 2) + j;
            float inv = 1.0f / lsum[(size_t)bb * S_ + m];
#pragma unroll
            for (int ni = 0; ni < 4; ++ni) {
                int n = ntt * 128 + wc * 64 + ni * 16 + (lane & 15);
                out[((size_t)bb * S_ + m) * E_ + n] = acc[mi][ni][j] * inv;
            }
        }
}

extern "C" void kernel_launch(void* const* d_in, const int* in_sizes, int n_in,
                              void* d_out, int out_size, void* d_ws, size_t ws_size,
                              hipStream_t stream) {
    const float* x = (const float*)d_in[0];
    const float* Wq = (const float*)d_in[1];
    const float* bq = (const float*)d_in[2];
    const float* Wk = (const float*)d_in[3];
    const float* bk = (const float*)d_in[4];
    const float* Wv = (const float*)d_in[5];
    const float* bv = (const float*)d_in[6];
    float* out = (float*)d_out;

    char* ws = (char*)d_ws;
    const size_t xb_off = 0;
    const size_t wb_off = xb_off + (size_t)M_ * E_ * 2;       // 64 MiB
    const size_t qkv_off = wb_off + (size_t)3 * E_ * E_ * 2;  // +6 MiB
    const size_t vt_off = qkv_off + (size_t)3 * M_ * E_ * 2;  // +192 MiB
    const size_t l_off = vt_off + (size_t)M_ * E_ * 2;        // +64 MiB
    const size_t chunk_off = l_off + (size_t)M_ * 4;          // +128 KiB

    u16* xb = (u16*)(ws + xb_off);
    u16* Wb = (u16*)(ws + wb_off);
    u16* qkv = (u16*)(ws + qkv_off);
    u16* vt = (u16*)(ws + vt_off);
    float* lsum = (float*)(ws + l_off);

    int CH = 16;
    while (CH > 1 && chunk_off + (size_t)CH * S_ * S_ * 2 > ws_size) CH >>= 1;
    u16* Pbuf = (u16*)(ws + chunk_off);

    hipMemsetAsync(lsum, 0, (size_t)M_ * 4, stream);

    cvt_f32_bf16<<<2048, 256, 0, stream>>>(x, xb, M_ * E_ / 8);
    cvt_f32_bf16<<<512, 256, 0, stream>>>(Wq, Wb, E_ * E_ / 8);
    cvt_f32_bf16<<<512, 256, 0, stream>>>(Wk, Wb + E_ * E_, E_ * E_ / 8);
    cvt_f32_bf16<<<512, 256, 0, stream>>>(Wv, Wb + 2 * E_ * E_, E_ * E_ / 8);

    gemm_qkv<<<3072, 512, 0, stream>>>(xb, Wb, bq, bk, bv, qkv);
    transpose_v<<<16 * 32 * 16, 256, 0, stream>>>(qkv + (size_t)2 * M_ * E_, vt);

    for (int b0 = 0; b0 < B_; b0 += CH) {
        gemm_sexp<<<CH * 128, 512, 0, stream>>>(qkv, Pbuf, lsum, b0);
        gemm_pv<<<CH * 64, 512, 0, stream>>>(Pbuf, vt, lsum, out, b0);
    }
}